// Round 6
// baseline (451.284 us; speedup 1.0000x reference)
//
#include <hip/hip_runtime.h>
#include <cstddef>
#include <cstdint>

#define BZd   128
#define Td    32
#define Dd    768
#define DFFd  3072
#define Ed    8
#define NBEAM 256
#define ROWS_TOT 8192
#define OUT_ELEMS 6291456
#define MAXTILES 72

typedef unsigned short u16;
typedef __attribute__((ext_vector_type(4))) unsigned short ushort4v;
typedef __attribute__((ext_vector_type(8))) short frag_ab;
typedef __attribute__((ext_vector_type(4))) float floatx4;

__device__ __forceinline__ u16 f2bf(float f) {
  unsigned int u = __builtin_bit_cast(unsigned int, f);
  u += 0x7FFFu + ((u >> 16) & 1u);
  return (u16)(u >> 16);
}

__device__ __forceinline__ void async_copy16(u16* lds, const u16* g) {
  __builtin_amdgcn_global_load_lds(
      (const __attribute__((address_space(1))) void*)g,
      (__attribute__((address_space(3))) void*)lds, 16, 0, 0);
}

// fast gelu (tanh form via sigmoid): max abs err ~3e-4, << 0.14 threshold
__device__ __forceinline__ float gelu_fast(float x) {
  float z = 1.5957691216f * (x + 0.044715f * x * x * x);
  return x / (1.0f + __expf(-z));
}

// ---------------------------------------------------------------------------
// Routing + x conversion fused (round-5, verified). Routing math byte-identical
// to rounds 2-5 — near-tie softmax, do not perturb accumulation order.
// ---------------------------------------------------------------------------
__global__ __launch_bounds__(256) void route_convert_kernel(
    const float* __restrict__ x, const float* __restrict__ Wg,
    float* __restrict__ out, int* __restrict__ sel, u16* __restrict__ xbf) {
  int b = blockIdx.x;
  int t = threadIdx.x;
  __shared__ float red[256][8];
  float la[8];
#pragma unroll
  for (int e = 0; e < 8; e++) la[e] = 0.f;
  for (int d = t; d < Dd; d += 256) {
    const float* xp = x + (size_t)b * Td * Dd + d;
    float xa = 0.f;
#pragma unroll
    for (int tt = 0; tt < Td; tt++) xa += xp[(size_t)tt * Dd];
    xa *= (1.0f / 32.0f);
#pragma unroll
    for (int e = 0; e < 8; e++) la[e] += xa * Wg[d * 8 + e];
  }
#pragma unroll
  for (int e = 0; e < 8; e++) red[t][e] = la[e];
  __syncthreads();
  for (int s = 128; s > 0; s >>= 1) {
    if (t < s) {
#pragma unroll
      for (int e = 0; e < 8; e++) red[t][e] += red[t + s][e];
    }
    __syncthreads();
  }
  if (t == 0) {
    float lg[8];
#pragma unroll
    for (int e = 0; e < 8; e++) lg[e] = red[0][e];
    float mx = lg[0];
#pragma unroll
    for (int e = 1; e < 8; e++) mx = fmaxf(mx, lg[e]);
    float p[8];
    float sum = 0.f;
#pragma unroll
    for (int e = 0; e < 8; e++) { p[e] = __expf(lg[e] - mx); sum += p[e]; }
    float inv = 1.0f / sum;
#pragma unroll
    for (int e = 0; e < 8; e++) p[e] *= inv;
    int i0 = 0; float v0 = p[0];
#pragma unroll
    for (int e = 1; e < 8; e++) if (p[e] > v0) { v0 = p[e]; i0 = e; }
    int i1 = -1; float v1 = -1.0f;
#pragma unroll
    for (int e = 0; e < 8; e++) if (e != i0 && p[e] > v1) { v1 = p[e]; i1 = e; }
    float* bs = out + OUT_ELEMS;
    float* er = out + OUT_ELEMS + NBEAM;
    bs[2 * b] = v0; bs[2 * b + 1] = v1;
    er[2 * b] = (float)i0; er[2 * b + 1] = (float)i1;
    sel[2 * b] = i0; sel[2 * b + 1] = i1;
  }
  const float* xp = x + (size_t)b * Td * Dd;
  u16* op = xbf + (size_t)b * Td * Dd;
#pragma unroll
  for (int k = 0; k < 24; k++) {
    int flat = (k * 256 + t) * 4;
    float4 v = *(const float4*)(xp + flat);
    ushort4v pv = {f2bf(v.x), f2bf(v.y), f2bf(v.z), f2bf(v.w)};
    *(ushort4v*)(op + flat) = pv;
  }
}

// ---------------------------------------------------------------------------
// Bucket (round-5, verified)
// ---------------------------------------------------------------------------
__global__ __launch_bounds__(256) void bucket_kernel(
    const int* __restrict__ sel, int* __restrict__ perm, int4* __restrict__ tiles) {
  __shared__ int ssel[NBEAM];
  __shared__ int scnt[8];
  __shared__ int soff[8];
  __shared__ int sperm[NBEAM];
  int t = threadIdx.x;
  ssel[t] = sel[t];
  __syncthreads();
  if (t == 0) {
    for (int e = 0; e < 8; e++) scnt[e] = 0;
    for (int n = 0; n < NBEAM; n++) scnt[ssel[n]]++;
    int o = 0;
    for (int e = 0; e < 8; e++) { soff[e] = o; o += scnt[e]; }
  }
  __syncthreads();
  if (t < 8) {
    int idx = soff[t];
    for (int n = 0; n < NBEAM; n++)
      if (ssel[n] == t) sperm[idx++] = n;
  }
  if (t == 0) {
    int tt = 0;
    for (int e = 0; e < 8; e++) {
      int nr = scnt[e] * 32;
      int base = soff[e] * 32;
      for (int r0 = 0; r0 < nr; r0 += 128) {
        tiles[tt] = make_int4(e, base + r0, min(128, nr - r0), 0);
        tt++;
      }
    }
    for (; tt < MAXTILES; tt++) tiles[tt] = make_int4(-1, 0, 0, 0);
  }
  __syncthreads();
  perm[t] = sperm[t];
}

// ---------------------------------------------------------------------------
// Unified weight transpose + fp32->bf16 (round-5, verified)
// ---------------------------------------------------------------------------
__global__ __launch_bounds__(256) void transpose_all_kernel(
    const float* __restrict__ W1, u16* __restrict__ w1t,
    const float* __restrict__ W2, u16* __restrict__ w2t, int f0, int FC) {
  __shared__ u16 tile[64][65];
  int z = blockIdx.z, bx = blockIdx.x, by = blockIdx.y;
  int t = threadIdx.x;
  const float* ip; u16* op; int ld_in, ld_out;
  if (z < 8) {
    int e = z;
    ld_in = DFFd; ld_out = Dd;
    ip = W1 + (size_t)e * Dd * DFFd + (size_t)(bx * 64) * DFFd + (f0 + by * 64);
    op = w1t + (size_t)e * FC * Dd + (size_t)(by * 64) * Dd + bx * 64;
  } else {
    int e = z - 8;
    ld_in = Dd; ld_out = FC;
    ip = W2 + (size_t)e * DFFd * Dd + (size_t)(f0 + by * 64) * Dd + bx * 64;
    op = w2t + (size_t)e * Dd * FC + (size_t)(bx * 64) * FC + by * 64;
  }
  int rr = t >> 4, cc4 = (t & 15) * 4;
#pragma unroll
  for (int i = 0; i < 4; i++) {
    int r = rr + 16 * i;
    float4 v = *(const float4*)(ip + (size_t)r * ld_in + cc4);
    tile[r][cc4 + 0] = f2bf(v.x);
    tile[r][cc4 + 1] = f2bf(v.y);
    tile[r][cc4 + 2] = f2bf(v.z);
    tile[r][cc4 + 3] = f2bf(v.w);
  }
  __syncthreads();
  int ccw = t >> 4, r4 = (t & 15) * 4;
#pragma unroll
  for (int i = 0; i < 4; i++) {
    int cc = ccw + 16 * i;
    ushort4v pv = {tile[r4 + 0][cc], tile[r4 + 1][cc], tile[r4 + 2][cc], tile[r4 + 3][cc]};
    *(ushort4v*)(op + (size_t)cc * ld_out + r4) = pv;
  }
}

// ---------------------------------------------------------------------------
// GEMM1: h = gelu(X @ W1T^T + b1). Tile 128(M)x256(N), BK=64, single-buffer
// 2-barrier (round-4 skeleton — dbuf regressed, see round-5). 64 MFMA per
// wave per drain. Wave wn owns 64 N-cols; all waves share A. LDS 48 KB.
// XOR chunk-swizzle (c ^ (row>>1)&7) at stage & read -> 2-way banks (free).
// ---------------------------------------------------------------------------
__global__ __launch_bounds__(256) void gemm1_kernel(
    const u16* __restrict__ xbf, const u16* __restrict__ w1t,
    const float* __restrict__ b1, const int* __restrict__ perm,
    const int4* __restrict__ tiles, u16* __restrict__ h, int f0, int FC) {
  int4 meta = tiles[blockIdx.y];
  int e = meta.x;
  if (e < 0) return;
  int grow0 = meta.y, nrows = meta.z;
  int bx = blockIdx.x;

  __shared__ __align__(16) u16 As[128 * 64];   // 16 KB
  __shared__ __align__(16) u16 Bs[256 * 64];   // 32 KB

  int t = threadIdx.x;
  int l = t & 63, w = t >> 6;
  int lrow = l & 15, lquad = l >> 4;

  // A staging: 1024 slots of 16B; slot s -> row m=s>>3, chunk (s&7)^((m>>1)&7)
  const u16* ag[4];
  int albase[4];
#pragma unroll
  for (int j = 0; j < 4; j++) {
    int s = j * 256 + t;
    int m = s >> 3;
    int koff = ((s & 7) ^ ((m >> 1) & 7)) * 8;
    int bidx = (grow0 >> 5) + (m >> 5);
    bidx = bidx < NBEAM ? bidx : NBEAM - 1;
    int batch = perm[bidx] >> 1;
    ag[j] = xbf + ((size_t)batch * Td + (m & 31)) * Dd + koff;
    albase[j] = (j * 256 + w * 64) * 8;
  }
  // B staging: 2048 slots (256 rows)
  const u16* bg[8];
  int blbase[8];
#pragma unroll
  for (int j = 0; j < 8; j++) {
    int s = j * 256 + t;
    int m = s >> 3;
    int koff = ((s & 7) ^ ((m >> 1) & 7)) * 8;
    bg[j] = w1t + ((size_t)e * FC + bx * 256 + m) * Dd + koff;
    blbase[j] = (j * 256 + w * 64) * 8;
  }

  int aoff[2][8], boff[2][4];
#pragma unroll
  for (int hh = 0; hh < 2; hh++) {
#pragma unroll
    for (int mi = 0; mi < 8; mi++) {
      int ra = mi * 16 + lrow;
      aoff[hh][mi] = ra * 64 + (((lquad + hh * 4) ^ ((ra >> 1) & 7)) * 8);
    }
#pragma unroll
    for (int ni = 0; ni < 4; ni++) {
      int rb = w * 64 + ni * 16 + lrow;
      boff[hh][ni] = rb * 64 + (((lquad + hh * 4) ^ ((rb >> 1) & 7)) * 8);
    }
  }

  floatx4 acc[8][4];
#pragma unroll
  for (int mi = 0; mi < 8; mi++)
#pragma unroll
    for (int ni = 0; ni < 4; ni++) acc[mi][ni] = (floatx4){0.f, 0.f, 0.f, 0.f};

  for (int kt = 0; kt < Dd; kt += 64) {
#pragma unroll
    for (int j = 0; j < 4; j++) { async_copy16(&As[albase[j]], ag[j]); ag[j] += 64; }
#pragma unroll
    for (int j = 0; j < 8; j++) { async_copy16(&Bs[blbase[j]], bg[j]); bg[j] += 64; }
    __syncthreads();
#pragma unroll
    for (int hh = 0; hh < 2; hh++) {
      frag_ab af[8], bf[4];
#pragma unroll
      for (int mi = 0; mi < 8; mi++) af[mi] = *(const frag_ab*)(&As[aoff[hh][mi]]);
#pragma unroll
      for (int ni = 0; ni < 4; ni++) bf[ni] = *(const frag_ab*)(&Bs[boff[hh][ni]]);
#pragma unroll
      for (int mi = 0; mi < 8; mi++)
#pragma unroll
        for (int ni = 0; ni < 4; ni++)
          acc[mi][ni] = __builtin_amdgcn_mfma_f32_16x16x32_bf16(af[mi], bf[ni], acc[mi][ni], 0, 0, 0);
    }
    __syncthreads();
  }

  int f_base = bx * 256;
#pragma unroll
  for (int mi = 0; mi < 8; mi++) {
    int row0 = mi * 16 + lquad * 4;
#pragma unroll
    for (int ni = 0; ni < 4; ni++) {
      int col = w * 64 + ni * 16 + lrow;
      float bias = b1[(size_t)e * DFFd + f0 + f_base + col];
#pragma unroll
      for (int r = 0; r < 4; r++) {
        int row = row0 + r;
        if (row < nrows) {
          float vv = acc[mi][ni][r] + bias;
          h[(size_t)(grow0 + row) * FC + f_base + col] = f2bf(gelu_fast(vv));
        }
      }
    }
  }
}

// ---------------------------------------------------------------------------
// GEMM2: out = h @ W2T^T + b2. Tile 128x128, BK=128 (64 KB LDS, 64 MFMA per
// wave per drain, 24 iters at FC=3072). Single-buffer 2-barrier. No atomics.
// ---------------------------------------------------------------------------
__global__ __launch_bounds__(256) void gemm2_kernel(
    const u16* __restrict__ h, const u16* __restrict__ w2t,
    const float* __restrict__ b2, const int* __restrict__ perm,
    const int4* __restrict__ tiles, float* __restrict__ out,
    int FC, int first) {
  int4 meta = tiles[blockIdx.y];
  int e = meta.x;
  if (e < 0) return;
  int grow0 = meta.y, nrows = meta.z;
  int bx = blockIdx.x;

  __shared__ __align__(16) u16 As[128 * 128];  // 32 KB
  __shared__ __align__(16) u16 Bs[128 * 128];  // 32 KB
  __shared__ int sbeam[4];

  int t = threadIdx.x;
  if (t < 4) {
    int idx = (grow0 >> 5) + t;
    sbeam[t] = perm[idx < NBEAM ? idx : NBEAM - 1];
  }
  int l = t & 63, w = t >> 6;
  int wm = w & 1, wn = w >> 1;
  int lrow = l & 15, lquad = l >> 4;

  // staging: 2048 slots each; slot s -> row m=s>>4, chunk (s&15)^((m>>1)&7)
  const u16* ag[8]; const u16* bg[8];
  int lbase[8];
#pragma unroll
  for (int j = 0; j < 8; j++) {
    int s = j * 256 + t;
    int m = s >> 4;
    int koff = ((s & 15) ^ ((m >> 1) & 7)) * 8;
    int arow = grow0 + m;
    arow = arow < ROWS_TOT ? arow : ROWS_TOT - 1;
    ag[j] = h + (size_t)arow * FC + koff;
    bg[j] = w2t + ((size_t)e * Dd + bx * 128 + m) * FC + koff;
    lbase[j] = (j * 256 + w * 64) * 8;
  }

  int aoff[4][4], boff[4][4];
#pragma unroll
  for (int hh = 0; hh < 4; hh++)
#pragma unroll
    for (int i = 0; i < 4; i++) {
      int ra = wm * 64 + i * 16 + lrow;
      aoff[hh][i] = ra * 128 + (((lquad + hh * 4) ^ ((ra >> 1) & 7)) * 8);
      int rb = wn * 64 + i * 16 + lrow;
      boff[hh][i] = rb * 128 + (((lquad + hh * 4) ^ ((rb >> 1) & 7)) * 8);
    }

  floatx4 acc[4][4];
#pragma unroll
  for (int mi = 0; mi < 4; mi++)
#pragma unroll
    for (int ni = 0; ni < 4; ni++) acc[mi][ni] = (floatx4){0.f, 0.f, 0.f, 0.f};

  for (int kt = 0; kt < FC; kt += 128) {
#pragma unroll
    for (int j = 0; j < 8; j++) {
      async_copy16(&As[lbase[j]], ag[j]);
      async_copy16(&Bs[lbase[j]], bg[j]);
      ag[j] += 128; bg[j] += 128;
    }
    __syncthreads();
#pragma unroll
    for (int hh = 0; hh < 4; hh++) {
      frag_ab af[4], bf[4];
#pragma unroll
      for (int mi = 0; mi < 4; mi++) af[mi] = *(const frag_ab*)(&As[aoff[hh][mi]]);
#pragma unroll
      for (int ni = 0; ni < 4; ni++) bf[ni] = *(const frag_ab*)(&Bs[boff[hh][ni]]);
#pragma unroll
      for (int mi = 0; mi < 4; mi++)
#pragma unroll
        for (int ni = 0; ni < 4; ni++)
          acc[mi][ni] = __builtin_amdgcn_mfma_f32_16x16x32_bf16(af[mi], bf[ni], acc[mi][ni], 0, 0, 0);
    }
    __syncthreads();
  }

#pragma unroll
  for (int mi = 0; mi < 4; mi++) {
    int row0 = wm * 64 + mi * 16 + lquad * 4;
#pragma unroll
    for (int ni = 0; ni < 4; ni++) {
      int col = wn * 64 + ni * 16 + lrow;
      int dg = bx * 128 + col;
      float bias = b2[(size_t)e * Dd + dg];
#pragma unroll
      for (int r = 0; r < 4; r++) {
        int row = row0 + r;
        if (row < nrows) {
          int beam = sbeam[row >> 5];
          size_t o = ((size_t)beam * Td + (row & 31)) * Dd + dg;
          if (first) out[o] = acc[mi][ni][r] + bias;
          else out[o] += acc[mi][ni][r];
        }
      }
    }
  }
}

// ---------------------------------------------------------------------------
extern "C" void kernel_launch(void* const* d_in, const int* in_sizes, int n_in,
                              void* d_out, int out_size, void* d_ws, size_t ws_size,
                              hipStream_t stream) {
  const float* x  = (const float*)d_in[0];
  const float* Wg = (const float*)d_in[2];
  const float* W1 = (const float*)d_in[3];
  const float* b1 = (const float*)d_in[4];
  const float* W2 = (const float*)d_in[5];
  const float* b2 = (const float*)d_in[6];
  float* out = (float*)d_out;

  char* ws = (char*)d_ws;
  int*  sel   = (int*)ws;
  int*  perm  = sel + NBEAM;
  int4* tiles = (int4*)(ws + 4096);

  const size_t xbf_off = 65536;
  const size_t xbf_bytes = (size_t)BZd * Td * Dd * 2;
  int FC = 768;   // min chunk (divisible by 256 for gemm1 N-tile and 128 for gemm2 BK)
  if      (xbf_off + xbf_bytes + (size_t)40960 * 3072 <= ws_size) FC = 3072;
  else if (xbf_off + xbf_bytes + (size_t)40960 * 1536 <= ws_size) FC = 1536;
  int NC = DFFd / FC;

  u16* xbf = (u16*)(ws + xbf_off);
  u16* w1t = (u16*)(ws + xbf_off + xbf_bytes);
  u16* w2t = w1t + (size_t)Ed * FC * Dd;
  u16* h   = w2t + (size_t)Ed * Dd * FC;

  route_convert_kernel<<<BZd, 256, 0, stream>>>(x, Wg, out, sel, xbf);
  bucket_kernel<<<1, 256, 0, stream>>>(sel, perm, tiles);

  for (int c = 0; c < NC; c++) {
    transpose_all_kernel<<<dim3(Dd / 64, FC / 64, 16), 256, 0, stream>>>(
        W1, w1t, W2, w2t, c * FC, FC);
    gemm1_kernel<<<dim3(FC / 256, MAXTILES), 256, 0, stream>>>(
        xbf, w1t, b1, perm, tiles, h, c * FC, FC);
    gemm2_kernel<<<dim3(Dd / 128, MAXTILES), 256, 0, stream>>>(
        h, w2t, b2, perm, tiles, out, FC, c == 0 ? 1 : 0);
  }
}